// Round 11
// baseline (244.558 us; speedup 1.0000x reference)
//
#include <hip/hip_runtime.h>

// GeometricMultiHeadAttention — MI355X bf16 pipeline, dtype-agnostic inputs
// B=2 L=1024 D=1024 H=16 HD=64 NBUCKETS=64
// R22: R21 (proven best, 243.9us) + k_convert restructure ONLY:
//      - k_convert: 2049 blocks (2048 z-pack + 1 detect/flag/small-vectors)
//      - k_park: 1152 blocks x 8 rows, fp32-only x/weight parking; in bf16
//        mode each block reads flag (stream-ordered) and exits — replaces
//        9216 parasite blocks that ran ballot+atomic+2 barriers each.
//      All other kernels byte-identical to R21. RULE retained: never tighten
//      launch_bounds on a counted-vmcnt kernel (R20 spill race).

typedef __attribute__((ext_vector_type(8))) short short8;   // 8 bf16
typedef __attribute__((ext_vector_type(4))) short short4v;  // 4 bf16
typedef __attribute__((ext_vector_type(4))) float f32x4;    // 4 fp32

struct W6 { const unsigned short* p[6]; };
struct Src13 { const void* p[13]; };

__device__ __forceinline__ float bf2f(unsigned short u){
  union { unsigned u32; float f; } v; v.u32 = ((unsigned)u) << 16; return v.f;
}
__device__ __forceinline__ unsigned short f2bf(float f){
  unsigned u = __float_as_uint(f);
  u += 0x7FFFu + ((u >> 16) & 1u);            // RNE
  return (unsigned short)(u >> 16);
}
__device__ __forceinline__ unsigned short f2bf_rz(float f){
  return (unsigned short)(__float_as_uint(f) >> 16);   // trunc (f >= 0 here)
}
__device__ __forceinline__ void async16(const void* g, void* l){
  __builtin_amdgcn_global_load_lds(
      (const __attribute__((address_space(1))) unsigned int*)g,
      (__attribute__((address_space(3))) unsigned int*)l, 16, 0, 0);
}
__device__ __forceinline__ f32x4 mfma16(short8 a, short8 b, f32x4 c){
  return __builtin_amdgcn_mfma_f32_16x16x32_bf16(a, b, c, 0, 0, 0);
}
// freqs[i] = 2*pi / exp(i*ln(10000)/31), i in [0,32)
__device__ __forceinline__ float freq_of(int dd){
  return 6.283185307179586f * __expf(-0.29710775393471563f * (float)dd);
}

// Park element offsets (u16 units)
#define PX   0
#define PW(i) (2097152 + (i) * 1048576)   // i=0..6 : Wq Wk Wv Wo cWq cWk cWv
#define PQG  9437184
#define PQB  9438208
#define PKG  9439232
#define PKB  9440256
#define PBI  9441280
#define PARK_TOTAL 9442304                // elements

// ---------------------------------------------------------------------------
// K0a: z-pack (2048 blocks) + one block that detects dtype (writes flag) and
// parks the 5 small vectors (qg qb kg kb attn_bias).
// ---------------------------------------------------------------------------
__global__ __launch_bounds__(256) void k_convert(
    Src13 src, unsigned short* __restrict__ park,
    const int* __restrict__ z, unsigned char* __restrict__ zpk,
    int* __restrict__ flag)
{
  const int t = threadIdx.x;
  const int bid = blockIdx.x;
  if (bid < 2048) {                        // z packing blocks
    int base = bid * 1024 + t * 4;
    int4 zv = *(const int4*)(z + base);
    unsigned int pk = (unsigned)zv.x | ((unsigned)zv.y << 8) |
                      ((unsigned)zv.z << 16) | ((unsigned)zv.w << 24);
    *(unsigned int*)(zpk + base) = pk;
    return;
  }
  // bid == 2048: dtype detect + small-vector parking
  __shared__ int shcnt;
  if (t == 0) shcnt = 0;
  __syncthreads();
  const unsigned short* xr = (const unsigned short*)src.p[0];
  int e = (xr[2 * t] >> 7) & 0xFF;
  unsigned long long m = __ballot(e >= 132);
  if ((t & 63) == 0) atomicAdd(&shcnt, __popcll(m));
  __syncthreads();
  const bool isf32 = shcnt > 64;
  if (t == 0) *flag = isf32 ? 1 : 0;
  static const __device__ int segbase5[5] = { PQG, PQB, PKG, PKB, PBI };
  #pragma unroll
  for (int s5 = 0; s5 < 5; s5++) {
    unsigned short* dst = park + segbase5[s5] + t * 4;
    if (isf32) {
      const float* s = (const float*)src.p[8 + s5] + t * 4;
      f32x4 v = *(const f32x4*)s;
      short4v o;
      o.x = (short)f2bf(v.x); o.y = (short)f2bf(v.y);
      o.z = (short)f2bf(v.z); o.w = (short)f2bf(v.w);
      *(short4v*)dst = o;
    } else {
      const unsigned short* s = (const unsigned short*)src.p[8 + s5] + t * 4;
      *(short4v*)dst = *(const short4v*)s;
    }
  }
}

// ---------------------------------------------------------------------------
// K0b: fp32-only parking of x + 7 weights into bf16 park (8 rows per block).
// bf16 mode: flag==0 -> immediate exit (1152 trivial blocks).
// ---------------------------------------------------------------------------
__global__ __launch_bounds__(256) void k_park(
    Src13 src, unsigned short* __restrict__ park, const int* __restrict__ flag)
{
  if (*flag == 0) return;
  const int t = threadIdx.x;
  static const __device__ int segbase8[8] = {
    PX, PW(0), PW(1), PW(2), PW(3), PW(4), PW(5), PW(6) };
  #pragma unroll
  for (int i = 0; i < 8; i++) {
    int gr = blockIdx.x * 8 + i;           // 0..9215
    int seg   = (gr < 2048) ? 0  : 1 + ((gr - 2048) >> 10);
    int inner = (gr < 2048) ? gr : ((gr - 2048) & 1023);
    const float* s = (const float*)src.p[seg] + inner * 1024 + t * 4;
    f32x4 v = *(const f32x4*)s;
    short4v o;
    o.x = (short)f2bf(v.x); o.y = (short)f2bf(v.y);
    o.z = (short)f2bf(v.z); o.w = (short)f2bf(v.w);
    *(short4v*)(park + segbase8[seg] + inner * 1024 + t * 4) = o;
  }
}

// ---------------------------------------------------------------------------
// K1: Y[2048,6144] bf16 = X[2048,1024] @ [Wq Wk Wv cWq cWk cWv]^T
// R16-proven: 128x128 tile, 2-phase double-buffer, two barriers, vmcnt(4),
// XCD-bijective swizzle (768 = 8 x 96). X/W base selected by flag.
// launch_bounds(256,2): counted-vmcnt requires no spills (R20 lesson).
// ---------------------------------------------------------------------------
__global__ __launch_bounds__(256, 2) void k_proj_gemm(
    const unsigned short* __restrict__ Xpark, const unsigned short* __restrict__ Xdir,
    W6 w6park, W6 w6dir, const int* __restrict__ flag,
    unsigned short* __restrict__ Y)
{
  __shared__ unsigned short As[2][128 * 32];
  __shared__ unsigned short Bs[2][128 * 32];
  const int t = threadIdx.x;
  const int lane = t & 63, wid = t >> 6;
  const int f32m = *flag;
  const unsigned short* X = f32m ? Xpark : Xdir;
  int bid = blockIdx.y * 16 + blockIdx.x;
  bid = (bid & 7) * 96 + (bid >> 3);            // XCD chunking (768 % 8 == 0)
  const int m0 = (bid & 15) * 128;
  const int bn = bid >> 4;                      // 0..47
  const unsigned short* W = f32m ? w6park.p[bn >> 3] : w6dir.p[bn >> 3];
  const int nw0 = (bn & 7) * 128;
  const int waveM = (wid & 1) * 64, waveN = (wid >> 1) * 64;
  const int g = lane >> 4, c16 = lane & 15;
  const int srow = t >> 2, scol = (t & 3) * 8;

  f32x4 acc[4][4];
  #pragma unroll
  for (int i = 0; i < 4; i++)
    #pragma unroll
    for (int j = 0; j < 4; j++) acc[i][j] = f32x4{0.f, 0.f, 0.f, 0.f};

#define PSTAGE(bi, k0_) do { \
    async16(X + (size_t)(m0 + srow) * 1024 + (k0_) + scol,       (char*)As[bi] + t * 16); \
    async16(X + (size_t)(m0 + 64 + srow) * 1024 + (k0_) + scol,  (char*)As[bi] + 4096 + t * 16); \
    async16(W + (size_t)(nw0 + srow) * 1024 + (k0_) + scol,      (char*)Bs[bi] + t * 16); \
    async16(W + (size_t)(nw0 + 64 + srow) * 1024 + (k0_) + scol, (char*)Bs[bi] + 4096 + t * 16); \
  } while (0)

  PSTAGE(0, 0);
  for (int k0 = 0; k0 < 1024; k0 += 32) {
    const int cur = (k0 >> 5) & 1;
    if (k0 < 992) {
      PSTAGE(cur ^ 1, k0 + 32);                 // prefetch next K-tile
      __builtin_amdgcn_sched_barrier(0);
      asm volatile("s_waitcnt vmcnt(4)" ::: "memory");   // current tile landed
    } else {
      __builtin_amdgcn_sched_barrier(0);
      asm volatile("s_waitcnt vmcnt(0)" ::: "memory");
    }
    __builtin_amdgcn_s_barrier();
    __builtin_amdgcn_sched_barrier(0);
    short8 af[4], bfr[4];
    #pragma unroll
    for (int mt = 0; mt < 4; mt++)
      af[mt] = *(const short8*)(As[cur] + (waveM + mt * 16 + c16) * 32 + g * 8);
    #pragma unroll
    for (int nt = 0; nt < 4; nt++)
      bfr[nt] = *(const short8*)(Bs[cur] + (waveN + nt * 16 + c16) * 32 + g * 8);
    #pragma unroll
    for (int mt = 0; mt < 4; mt++)
      #pragma unroll
      for (int nt = 0; nt < 4; nt++)
        acc[mt][nt] = mfma16(af[mt], bfr[nt], acc[mt][nt]);
    __builtin_amdgcn_sched_barrier(0);
    __builtin_amdgcn_s_barrier();               // reads done before next stage
  }
#undef PSTAGE
  const int n0 = bn * 128;
  #pragma unroll
  for (int mt = 0; mt < 4; mt++)
    #pragma unroll
    for (int nt = 0; nt < 4; nt++)
      #pragma unroll
      for (int r = 0; r < 4; r++) {
        int row = m0 + waveM + mt * 16 + g * 4 + r;
        int col = n0 + waveN + nt * 16 + c16;
        Y[(size_t)row * 6144 + col] = f2bf(acc[mt][nt][r]);
      }
}

// ---------------------------------------------------------------------------
// K2: per (b,l) row: LN+rope(q,k), rope(v), copy(cq,ck,cv); transpose layouts.
// R16-proven body + R21 XCD-bijective block remap (2048 = 8 x 256).
// ---------------------------------------------------------------------------
__global__ __launch_bounds__(256) void k_post(
    const unsigned short* __restrict__ Y,
    const unsigned short* __restrict__ qg, const unsigned short* __restrict__ qbv,
    const unsigned short* __restrict__ kg, const unsigned short* __restrict__ kbv,
    const int* __restrict__ idx,
    unsigned short* __restrict__ qo, unsigned short* __restrict__ ko,
    unsigned short* __restrict__ cqo, unsigned short* __restrict__ cko,
    unsigned short* __restrict__ vto, unsigned short* __restrict__ cvto)
{
  const int bidr = blockIdx.x;
  const int r = (bidr & 7) * 256 + (bidr >> 3);   // XCD-contiguous row stripes
  const int b = r >> 10, l = r & 1023;
  const int t = threadIdx.x;
  __shared__ float red[4];
  __shared__ float rowbuf[1024];
  __shared__ float tc[32], ts[32];
  const unsigned short* Yr = Y + (size_t)r * 6144;
  const float pos = (float)idx[r];

  if (t < 32) {
    float a = pos * freq_of(t);
    tc[t] = cosf(a);
    ts[t] = sinf(a);
  }
  __syncthreads();

  for (int sec = 0; sec < 2; sec++) {
    const unsigned short* src = Yr + sec * 1024;
    const unsigned short* gg = sec ? kg : qg;
    const unsigned short* bb = sec ? kbv : qbv;
    unsigned short* dst = sec ? ko : qo;
    float v0 = bf2f(src[t]), v1 = bf2f(src[t + 256]);
    float v2 = bf2f(src[t + 512]), v3 = bf2f(src[t + 768]);
    float s = v0 + v1 + v2 + v3;
    float s2 = v0 * v0 + v1 * v1 + v2 * v2 + v3 * v3;
    #pragma unroll
    for (int o = 32; o > 0; o >>= 1) {
      s += __shfl_down(s, o, 64);
      s2 += __shfl_down(s2, o, 64);
    }
    __syncthreads();
    if ((t & 63) == 0) red[t >> 6] = s;
    __syncthreads();
    float tot = red[0] + red[1] + red[2] + red[3];
    __syncthreads();
    if ((t & 63) == 0) red[t >> 6] = s2;
    __syncthreads();
    float tot2 = red[0] + red[1] + red[2] + red[3];
    float mu = tot * (1.f / 1024.f);
    float var = tot2 * (1.f / 1024.f) - mu * mu;
    float rstd = rsqrtf(var + 1e-5f);
    rowbuf[t]       = (v0 - mu) * rstd * bf2f(gg[t])       + bf2f(bb[t]);
    rowbuf[t + 256] = (v1 - mu) * rstd * bf2f(gg[t + 256]) + bf2f(bb[t + 256]);
    rowbuf[t + 512] = (v2 - mu) * rstd * bf2f(gg[t + 512]) + bf2f(bb[t + 512]);
    rowbuf[t + 768] = (v3 - mu) * rstd * bf2f(gg[t + 768]) + bf2f(bb[t + 768]);
    __syncthreads();
    #pragma unroll
    for (int j = 0; j < 4; j++) {
      int d = t + 256 * j;
      int h = d >> 6, dd = d & 63;
      float c = tc[dd & 31], sn = ts[dd & 31];
      float x1 = rowbuf[d];
      float x2 = rowbuf[(d & ~63) | ((dd + 32) & 63)];
      float res = (dd < 32) ? (x1 * c - x2 * sn) : (x1 * c + x2 * sn);
      dst[((size_t)(b * 16 + h) * 1024 + l) * 64 + dd] = f2bf(res);
    }
  }
  {
    const unsigned short* src = Yr + 2048;
    __syncthreads();
    rowbuf[t] = bf2f(src[t]); rowbuf[t + 256] = bf2f(src[t + 256]);
    rowbuf[t + 512] = bf2f(src[t + 512]); rowbuf[t + 768] = bf2f(src[t + 768]);
    __syncthreads();
    #pragma unroll
    for (int j = 0; j < 4; j++) {
      int d = t + 256 * j;
      int h = d >> 6, dd = d & 63;
      float c = tc[dd & 31], sn = ts[dd & 31];
      float x1 = rowbuf[d];
      float x2 = rowbuf[(d & ~63) | ((dd + 32) & 63)];
      float res = (dd < 32) ? (x1 * c - x2 * sn) : (x1 * c + x2 * sn);
      vto[((size_t)(b * 16 + h) * 64 + dd) * 1024 + l] = f2bf(res);
    }
  }
  #pragma unroll
  for (int j = 0; j < 4; j++) {
    int d = t + 256 * j;
    int h = d >> 6, dd = d & 63;
    size_t km = ((size_t)(b * 16 + h) * 1024 + l) * 64 + dd;
    cqo[km] = Yr[3072 + d];
    cko[km] = Yr[4096 + d];
    cvto[((size_t)(b * 16 + h) * 64 + dd) * 1024 + l] = Yr[5120 + d];
  }
}

// ---------------------------------------------------------------------------
// K3: flash attention (no online max; LN'd q/k => bounded scores).
// R15 (unchanged): grid (8,32,2) = 512 blocks, 4 waves, 2 q-strips per wave
// with register fragment reuse; single-buffered chunk-64 staging + drain.
// ---------------------------------------------------------------------------
__global__ __launch_bounds__(256, 2) void k_attn(
    const unsigned short* __restrict__ qm, const unsigned short* __restrict__ km,
    const unsigned short* __restrict__ cqm, const unsigned short* __restrict__ ckm,
    const unsigned short* __restrict__ vt, const unsigned short* __restrict__ cvt,
    const int* __restrict__ chain, const int* __restrict__ mol,
    const unsigned char* __restrict__ zpk, const unsigned short* __restrict__ bias,
    float* __restrict__ Opart, float* __restrict__ lpart)
{
  const int q0 = blockIdx.x * 128;
  const int bh = blockIdx.y;
  const int seg = blockIdx.z;                 // 0..1
  const int b = bh >> 4, h = bh & 15;
  __shared__ float biasf[64];
  __shared__ unsigned char codek[512];
  __shared__ __align__(16) unsigned char zs[128 * 64];                // 8 KB
  __shared__ __align__(16) unsigned short Ks[64 * 64], cKs[64 * 64];  // 8 KB each
  __shared__ __align__(16) unsigned short Vs[64 * 64], cVs[64 * 64];  // 8 KB each
  __shared__ unsigned short Ps[4][2][16][36], Pc[4][2][16][36];       // 9 KB each
  const int t = threadIdx.x, lane = t & 63, w = t >> 6;   // w in 0..3
  const int g = lane >> 4, c16 = lane & 15;
  const int kbeg = seg * 512;

  if (t < 128) {
    int4 ch = *(const int4*)(chain + b * 1024 + kbeg + t * 4);
    int4 mo = *(const int4*)(mol   + b * 1024 + kbeg + t * 4);
    codek[t * 4 + 0] = mo.x ? 255 : (unsigned char)ch.x;
    codek[t * 4 + 1] = mo.y ? 255 : (unsigned char)ch.y;
    codek[t * 4 + 2] = mo.z ? 255 : (unsigned char)ch.z;
    codek[t * 4 + 3] = mo.w ? 255 : (unsigned char)ch.w;
  } else if (t < 192) {
    biasf[t - 128] = bf2f(bias[(t - 128) * 16 + h]);
  }

  const size_t basep = (size_t)bh << 16;      // bh * 64 * 1024
  int cqa[2][4];
  #pragma unroll
  for (int s = 0; s < 2; s++) {
    int4 cqv = *(const int4*)(chain + b * 1024 + q0 + s * 64 + w * 16 + g * 4);
    cqa[s][0] = cqv.x; cqa[s][1] = cqv.y; cqa[s][2] = cqv.z; cqa[s][3] = cqv.w;
  }

  // q / cq fragments: invariant across chunks — load once (32 VGPR).
  short8 aq0[2], aq1[2], acq0[2], acq1[2];
  #pragma unroll
  for (int s = 0; s < 2; s++) {
    const unsigned short* qrow  = qm  + basep + (size_t)(q0 + s * 64 + w * 16 + c16) * 64;
    const unsigned short* cqrow = cqm + basep + (size_t)(q0 + s * 64 + w * 16 + c16) * 64;
    aq0[s]  = *(const short8*)(qrow + g * 8);
    aq1[s]  = *(const short8*)(qrow + 32 + g * 8);
    acq0[s] = *(const short8*)(cqrow + g * 8);
    acq1[s] = *(const short8*)(cqrow + 32 + g * 8);
  }

  float l_[2][4];
  f32x4 Os[2][4], Oc[2][4];
  #pragma unroll
  for (int s = 0; s < 2; s++)
    #pragma unroll
    for (int nt = 0; nt < 4; nt++) {
      l_[s][nt] = 0.f;
      Os[s][nt] = f32x4{0.f, 0.f, 0.f, 0.f};
      Oc[s][nt] = f32x4{0.f, 0.f, 0.f, 0.f};
    }
  // Staging lane roles (R11/R12-proven patterns)
  const int Rk = t >> 3, jk = t & 7;          // K/V tiles: 32 rows x 8 groups/issue
  const int Rz = t >> 2, jz = t & 3;          // zs: 64 rows x 4 groups/issue
  const int swz16 = (jz ^ ((Rz >> 2) & 3)) * 16;      // byte offset, zs swizzle
  const f32x4 zero = f32x4{0.f, 0.f, 0.f, 0.f};
  __syncthreads();   // codek/biasf ready

  for (int kc = 0; kc < 8; kc++) {
    const int kt = kbeg + kc * 64;
    // stage zs (128 q-rows x 64 keys, this chunk), group-swizzled source
    #pragma unroll
    for (int i = 0; i < 2; i++)
      async16(zpk + (size_t)b * 1048576 + (size_t)(q0 + i * 64 + Rz) * 1024
                  + kt + swz16,
              (char*)zs + i * 4096 + t * 16);
    // stage K/cK (64 keys x 64 d) and V/cV (64 d x 64 keys), swizzled
    #pragma unroll
    for (int i = 0; i < 2; i++) {
      int row = i * 32 + Rk;
      int srcb = jk ^ (row & 7);
      async16(km  + basep + (size_t)(kt + row) * 64 + srcb * 8, (char*)Ks  + i * 4096 + t * 16);
      async16(ckm + basep + (size_t)(kt + row) * 64 + srcb * 8, (char*)cKs + i * 4096 + t * 16);
      async16(vt  + basep + (size_t)row * 1024 + kt + srcb * 8, (char*)Vs  + i * 4096 + t * 16);
      async16(cvt + basep + (size_t)row * 1024 + kt + srcb * 8, (char*)cVs + i * 4096 + t * 16);
    }
    __syncthreads();
    // --- per 32-key half: QK (frag-shared), exp per strip, PV (frag-shared)
    #pragma unroll
    for (int half = 0; half < 2; half++) {
      // scores for this half's 2 key-col-frags, both strips
      f32x4 sS[2][2], sC[2][2];
      #pragma unroll
      for (int nn = 0; nn < 2; nn++) {
        int R = (half * 2 + nn) * 16 + c16;
        int sw = R & 7;
        short8 kbl = *(const short8*)((char*)Ks  + R * 128 + ((g ^ sw) * 16));
        short8 kbh = *(const short8*)((char*)Ks  + R * 128 + (((4 + g) ^ sw) * 16));
        short8 cbl = *(const short8*)((char*)cKs + R * 128 + ((g ^ sw) * 16));
        short8 cbh = *(const short8*)((char*)cKs + R * 128 + (((4 + g) ^ sw) * 16));
        #pragma unroll
        for (int s = 0; s < 2; s++) {
          sS[s][nn] = mfma16(aq1[s], kbh, mfma16(aq0[s], kbl, zero));
          sC[s][nn] = mfma16(acq1[s], cbh, mfma16(acq0[s], cbl, zero));
        }
      }
      int cd0 = codek[kc * 64 + half * 32 + c16];
      int cd1 = codek[kc * 64 + half * 32 + 16 + c16];
      short8 aps[2], apc[2];
      #pragma unroll
      for (int s = 0; s < 2; s++) {
        #pragma unroll
        for (int r = 0; r < 4; r++) {
          const unsigned char* zr = zs + (s * 64 + w * 16 + g * 4 + r) * 64;
          // source group (half*2+k) lives at LDS group (half*2+k)^g for our rows
          float bi0 = biasf[zr[((half * 2) ^ g) * 16 + c16]];
          float bi1 = biasf[zr[((half * 2 + 1) ^ g) * 16 + c16]];
          bool sp0 = (cd0 == cqa[s][r]);
          bool sp1 = (cd1 == cqa[s][r]);
          float p0 = __expf(__fmaf_rn(sp0 ? sS[s][0][r] : sC[s][0][r], 0.125f, bi0));
          float p1 = __expf(__fmaf_rn(sp1 ? sS[s][1][r] : sC[s][1][r], 0.125f, bi1));
          l_[s][r] += p0 + p1;
          int lr = g * 4 + r;
          Ps[w][s][lr][c16]      = f2bf_rz(sp0 ? p0 : 0.f);
          Pc[w][s][lr][c16]      = f2bf_rz(sp0 ? 0.f : p0);
          Ps[w][s][lr][16 + c16] = f2bf_rz(sp1 ? p1 : 0.f);
          Pc[w][s][lr][16 + c16] = f2bf_rz(sp1 ? 0.f : p1);
        }
        aps[s] = *(const short8*)&Ps[w][s][c16][g * 8];
        apc[s] = *(const short8*)&Pc[w][s][c16][g * 8];
      }
      // PV: V-frags shared across strips
      #pragma unroll
      for (int nt = 0; nt < 4; nt++) {
        int R = nt * 16 + c16;
        int sw = R & 7;
        int J = half * 4 + g;
        short8 bv  = *(const short8*)((char*)Vs  + R * 128 + ((J ^ sw) * 16));
        short8 bcv = *(const short8*)((char*)cVs + R * 128 + ((J ^ sw) * 16));
        #pragma unroll
        for (int s = 0; s < 2; s++) {
          Os[s][nt] = mfma16(aps[s], bv,  Os[s][nt]);
          Oc[s][nt] = mfma16(apc[s], bcv, Oc[s][nt]);
        }
      }
    }
    __syncthreads();   // protect tiles/zs before next chunk's staging
  }

  // epilogue: reduce l across the quad-group lanes; store partials
  #pragma unroll
  for (int s = 0; s < 2; s++)
    #pragma unroll
    for (int r = 0; r < 4; r++) {
      float lv = l_[s][r];
      lv += __shfl_xor(lv, 1);
      lv += __shfl_xor(lv, 2);
      lv += __shfl_xor(lv, 4);
      lv += __shfl_xor(lv, 8);
      int row = q0 + s * 64 + w * 16 + g * 4 + r;
      float* op = Opart + (((size_t)seg * 32 + bh) * 1024 + row) * 128;
      #pragma unroll
      for (int nt = 0; nt < 4; nt++) {
        op[nt * 16 + c16]      = Os[s][nt][r];
        op[64 + nt * 16 + c16] = Oc[s][nt][r];
      }
      if (c16 == 0) lpart[((size_t)seg * 32 + bh) * 1024 + row] = lv;
    }
}

// ---------------------------------------------------------------------------
// K3b: combine 2 K-segment partials (linear), normalize, inverse rope, write
// comb (B,L,D) bf16.
// ---------------------------------------------------------------------------
__global__ __launch_bounds__(256) void k_combine(
    const float* __restrict__ Opart, const float* __restrict__ lpart,
    const int* __restrict__ idx, unsigned short* __restrict__ comb)
{
  const int t = threadIdx.x;
  const int rg = blockIdx.x * 8 + (t >> 5);   // global row id in [0, 32768)
  const int d = t & 31;
  const int bh = rg >> 10, row = rg & 1023;
  const int b = bh >> 4, h = bh & 15;
  float oslo = 0.f, oshi = 0.f, oclo = 0.f, ochi = 0.f, l = 0.f;
  #pragma unroll
  for (int seg = 0; seg < 2; seg++) {
    const float* op = Opart + (((size_t)seg * 32 + bh) * 1024 + row) * 128;
    oslo += op[d]; oshi += op[32 + d];
    oclo += op[64 + d]; ochi += op[96 + d];
    l += lpart[((size_t)seg * 32 + bh) * 1024 + row];
  }
  float inv = 1.f / l;
  float pos = (float)idx[b * 1024 + row];
  float fr = freq_of(d);
  float aa = -pos * fr;
  float cc = cosf(aa), sn = sinf(aa);
  size_t orow = ((size_t)(b * 1024 + row)) * 1024 + h * 64;
  comb[orow + d]      = f2bf((oslo * cc - oshi * sn + oclo) * inv);
  comb[orow + d + 32] = f2bf((oshi * cc + oslo * sn + ochi) * inv);
}

// ---------------------------------------------------------------------------
// K4: out = comb @ Wo^T ; store bf16 or fp32 depending on detected dtype.
// R16-proven: 64x128 tiles, 256 blocks, two-barrier 2-phase double-buffer,
// counted vmcnt(3), XCD-bijective swizzle. Wo base selected by flag.
// ---------------------------------------------------------------------------
__global__ __launch_bounds__(256, 2) void k_out_gemm(
    const unsigned short* __restrict__ A,
    const unsigned short* __restrict__ Wopark, const unsigned short* __restrict__ Wodir,
    const int* __restrict__ flag, void* __restrict__ outv)
{
  __shared__ unsigned short As[2][64 * 32];
  __shared__ unsigned short Bs[2][128 * 32];
  const int t = threadIdx.x;
  const int lane = t & 63, wid = t >> 6;
  const int f32out = *flag;
  const unsigned short* Wo = f32out ? Wopark : Wodir;
  int bid = blockIdx.y * 32 + blockIdx.x;
  bid = (bid & 7) * 32 + (bid >> 3);            // XCD chunking (256 % 8 == 0)
  const int m0 = (bid & 31) * 64;
  const int n0 = (bid >> 5) * 128;
  const int waveM = (wid & 1) * 32, waveN = (wid >> 1) * 64;
  const int g = lane >> 4, c16 = lane & 15;
  const int srow = t >> 2, scol = (t & 3) * 8;  // A: 64 rows x 4 col-groups
  f32x4 acc[2][4];
  #pragma unroll
  for (int i = 0; i < 2; i++)
    #pragma unroll
    for (int j = 0; j < 4; j++) acc[i][j] = f32x4{0.f, 0.f, 0.f, 0.f};

#define OSTAGE(bi, k0_) do { \
    async16(A  + (size_t)(m0 + srow) * 1024 + (k0_) + scol,       (char*)As[bi] + t * 16); \
    async16(Wo + (size_t)(n0 + srow) * 1024 + (k0_) + scol,       (char*)Bs[bi] + t * 16); \
    async16(Wo + (size_t)(n0 + 64 + srow) * 1024 + (k0_) + scol,  (char*)Bs[bi] + 4096 + t * 16); \
  } while (0)

  OSTAGE(0, 0);
  for (int k0 = 0; k0 < 1024; k0 += 32) {
    const int cur = (k0 >> 5) & 1;
    if (k0 < 992) {
      OSTAGE(cur ^ 1, k0 + 32);
      __builtin_amdgcn_sched_barrier(0);
      asm volatile("s_waitcnt vmcnt(3)" ::: "memory");
    } else {
      __builtin_amdgcn_sched_barrier(0);
      asm volatile("s_waitcnt vmcnt(0)" ::: "memory");
    }
    __builtin_amdgcn_s_barrier();
    __builtin_amdgcn_sched_barrier(0);
    short8 af[2], bfr[4];
    #pragma unroll
    for (int mt = 0; mt < 2; mt++)
      af[mt] = *(const short8*)(As[cur] + (waveM + mt * 16 + c16) * 32 + g * 8);
    #pragma unroll
    for (int nt = 0; nt < 4; nt++)
      bfr[nt] = *(const short8*)(Bs[cur] + (waveN + nt * 16 + c16) * 32 + g * 8);
    #pragma unroll
    for (int mt = 0; mt < 2; mt++)
      #pragma unroll
      for (int nt = 0; nt < 4; nt++)
        acc[mt][nt] = mfma16(af[mt], bfr[nt], acc[mt][nt]);
    __builtin_amdgcn_sched_barrier(0);
    __builtin_amdgcn_s_barrier();
  }
#undef OSTAGE
  #pragma unroll
  for (int mt = 0; mt < 2; mt++)
    #pragma unroll
    for (int nt = 0; nt < 4; nt++)
      #pragma unroll
      for (int r = 0; r < 4; r++) {
        int row = m0 + waveM + mt * 16 + g * 4 + r;
        int col = n0 + waveN + nt * 16 + c16;
        if (f32out) ((float*)outv)[(size_t)row * 1024 + col] = acc[mt][nt][r];
        else ((unsigned short*)outv)[(size_t)row * 1024 + col] = f2bf(acc[mt][nt][r]);
      }
}

// ---------------------------------------------------------------------------
extern "C" void kernel_launch(void* const* d_in, const int* in_sizes, int n_in,
                              void* d_out, int out_size, void* d_ws, size_t ws_size,
                              hipStream_t stream)
{
  (void)in_sizes; (void)n_in; (void)out_size; (void)ws_size;
  const int* z     = (const int*)d_in[1];
  const int* idx   = (const int*)d_in[3];
  const int* chain = (const int*)d_in[4];
  const int* mol   = (const int*)d_in[5];

  char* ws = (char*)d_ws;
  unsigned short* Y     = (unsigned short*)ws;              // 25 MB bf16
  size_t off = 50331648;
  unsigned short* qbuf  = (unsigned short*)(ws + off); off += 4194304;
  unsigned short* kbuf  = (unsigned short*)(ws + off); off += 4194304;
  unsigned short* cqbuf = (unsigned short*)(ws + off); off += 4194304;
  unsigned short* ckbuf = (unsigned short*)(ws + off); off += 4194304;
  unsigned short* vtbuf = (unsigned short*)(ws + off); off += 4194304;
  unsigned short* cvtbuf= (unsigned short*)(ws + off); off += 4194304;
  unsigned short* comb  = (unsigned short*)(ws + off); off += 4194304;
  unsigned short* park  = (unsigned short*)(ws + off); off += (size_t)PARK_TOTAL * 2;
  unsigned char*  zpk   = (unsigned char*)(ws + off); off += 2097152;
  float*          Opart = (float*)(ws + off); off += (size_t)2 * 32 * 1024 * 128 * 4;
  float*          lpart = (float*)(ws + off); off += (size_t)2 * 32 * 1024 * 4;
  int*            flag  = (int*)(ws + off);

  Src13 src;
  src.p[0]  = d_in[0];   // x
  src.p[1]  = d_in[6];   // Wq
  src.p[2]  = d_in[7];   // Wk
  src.p[3]  = d_in[8];   // Wv
  src.p[4]  = d_in[9];   // Wo
  src.p[5]  = d_in[10];  // cWq
  src.p[6]  = d_in[11];  // cWk
  src.p[7]  = d_in[12];  // cWv
  src.p[8]  = d_in[13];  // qg
  src.p[9]  = d_in[14];  // qb
  src.p[10] = d_in[15];  // kg
  src.p[11] = d_in[16];  // kb
  src.p[12] = d_in[17];  // attn_bias

  W6 w6park, w6dir;
  w6park.p[0] = park + PW(0);  // Wq
  w6park.p[1] = park + PW(1);  // Wk
  w6park.p[2] = park + PW(2);  // Wv
  w6park.p[3] = park + PW(4);  // cWq
  w6park.p[4] = park + PW(5);  // cWk
  w6park.p[5] = park + PW(6);  // cWv
  w6dir.p[0] = (const unsigned short*)d_in[6];   // Wq
  w6dir.p[1] = (const unsigned short*)d_in[7];   // Wk
  w6dir.p[2] = (const unsigned short*)d_in[8];   // Wv
  w6dir.p[3] = (const unsigned short*)d_in[10];  // cWq
  w6dir.p[4] = (const unsigned short*)d_in[11];  // cWk
  w6dir.p[5] = (const unsigned short*)d_in[12];  // cWv

  k_convert<<<2049, 256, 0, stream>>>(src, park, z, zpk, flag);
  k_park<<<1152, 256, 0, stream>>>(src, park, flag);
  k_proj_gemm<<<dim3(16, 48), 256, 0, stream>>>(
      park + PX, (const unsigned short*)d_in[0], w6park, w6dir, flag, Y);
  k_post<<<2048, 256, 0, stream>>>(Y, park + PQG, park + PQB, park + PKG, park + PKB,
                                   idx, qbuf, kbuf, cqbuf, ckbuf, vtbuf, cvtbuf);
  k_attn<<<dim3(8, 32, 2), 256, 0, stream>>>(qbuf, kbuf, cqbuf, ckbuf, vtbuf, cvtbuf,
                                             chain, mol, zpk, park + PBI,
                                             Opart, lpart);
  k_combine<<<4096, 256, 0, stream>>>(Opart, lpart, idx, comb);
  k_out_gemm<<<dim3(32, 8), 256, 0, stream>>>(
      comb, park + PW(3), (const unsigned short*)d_in[9], flag, d_out);
}

// Round 12
// 241.025 us; speedup vs baseline: 1.0147x; 1.0147x over previous
//
#include <hip/hip_runtime.h>

// GeometricMultiHeadAttention — MI355X bf16 pipeline, dtype-agnostic inputs
// B=2 L=1024 D=1024 H=16 HD=64 NBUCKETS=64
// R23: R22 base; ONE lever in k_attn: drop the per-strip [2] dim from Ps/Pc
//      (strips time-share one wave-private buffer — in-wave LDS ordering +
//      compiler-visible same-array dependency make write(s0)/read-aps0/
//      write(s1) safe with zero extra syncs). LDS 60.4KB -> 49.8KB =>
//      3 blocks/CU resident (was 2) — R11/R14-proven block-TLP stacked on
//      R15's strip reuse. All other kernels byte-identical to R22.

typedef __attribute__((ext_vector_type(8))) short short8;   // 8 bf16
typedef __attribute__((ext_vector_type(4))) short short4v;  // 4 bf16
typedef __attribute__((ext_vector_type(4))) float f32x4;    // 4 fp32

struct W6 { const unsigned short* p[6]; };
struct Src13 { const void* p[13]; };

__device__ __forceinline__ float bf2f(unsigned short u){
  union { unsigned u32; float f; } v; v.u32 = ((unsigned)u) << 16; return v.f;
}
__device__ __forceinline__ unsigned short f2bf(float f){
  unsigned u = __float_as_uint(f);
  u += 0x7FFFu + ((u >> 16) & 1u);            // RNE
  return (unsigned short)(u >> 16);
}
__device__ __forceinline__ unsigned short f2bf_rz(float f){
  return (unsigned short)(__float_as_uint(f) >> 16);   // trunc (f >= 0 here)
}
__device__ __forceinline__ void async16(const void* g, void* l){
  __builtin_amdgcn_global_load_lds(
      (const __attribute__((address_space(1))) unsigned int*)g,
      (__attribute__((address_space(3))) unsigned int*)l, 16, 0, 0);
}
__device__ __forceinline__ f32x4 mfma16(short8 a, short8 b, f32x4 c){
  return __builtin_amdgcn_mfma_f32_16x16x32_bf16(a, b, c, 0, 0, 0);
}
// freqs[i] = 2*pi / exp(i*ln(10000)/31), i in [0,32)
__device__ __forceinline__ float freq_of(int dd){
  return 6.283185307179586f * __expf(-0.29710775393471563f * (float)dd);
}

// Park element offsets (u16 units)
#define PX   0
#define PW(i) (2097152 + (i) * 1048576)   // i=0..6 : Wq Wk Wv Wo cWq cWk cWv
#define PQG  9437184
#define PQB  9438208
#define PKG  9439232
#define PKB  9440256
#define PBI  9441280
#define PARK_TOTAL 9442304                // elements

// ---------------------------------------------------------------------------
// K0a: z-pack (2048 blocks) + one block that detects dtype (writes flag) and
// parks the 5 small vectors (qg qb kg kb attn_bias).
// ---------------------------------------------------------------------------
__global__ __launch_bounds__(256) void k_convert(
    Src13 src, unsigned short* __restrict__ park,
    const int* __restrict__ z, unsigned char* __restrict__ zpk,
    int* __restrict__ flag)
{
  const int t = threadIdx.x;
  const int bid = blockIdx.x;
  if (bid < 2048) {                        // z packing blocks
    int base = bid * 1024 + t * 4;
    int4 zv = *(const int4*)(z + base);
    unsigned int pk = (unsigned)zv.x | ((unsigned)zv.y << 8) |
                      ((unsigned)zv.z << 16) | ((unsigned)zv.w << 24);
    *(unsigned int*)(zpk + base) = pk;
    return;
  }
  // bid == 2048: dtype detect + small-vector parking
  __shared__ int shcnt;
  if (t == 0) shcnt = 0;
  __syncthreads();
  const unsigned short* xr = (const unsigned short*)src.p[0];
  int e = (xr[2 * t] >> 7) & 0xFF;
  unsigned long long m = __ballot(e >= 132);
  if ((t & 63) == 0) atomicAdd(&shcnt, __popcll(m));
  __syncthreads();
  const bool isf32 = shcnt > 64;
  if (t == 0) *flag = isf32 ? 1 : 0;
  static const __device__ int segbase5[5] = { PQG, PQB, PKG, PKB, PBI };
  #pragma unroll
  for (int s5 = 0; s5 < 5; s5++) {
    unsigned short* dst = park + segbase5[s5] + t * 4;
    if (isf32) {
      const float* s = (const float*)src.p[8 + s5] + t * 4;
      f32x4 v = *(const f32x4*)s;
      short4v o;
      o.x = (short)f2bf(v.x); o.y = (short)f2bf(v.y);
      o.z = (short)f2bf(v.z); o.w = (short)f2bf(v.w);
      *(short4v*)dst = o;
    } else {
      const unsigned short* s = (const unsigned short*)src.p[8 + s5] + t * 4;
      *(short4v*)dst = *(const short4v*)s;
    }
  }
}

// ---------------------------------------------------------------------------
// K0b: fp32-only parking of x + 7 weights into bf16 park (8 rows per block).
// bf16 mode: flag==0 -> immediate exit (1152 trivial blocks).
// ---------------------------------------------------------------------------
__global__ __launch_bounds__(256) void k_park(
    Src13 src, unsigned short* __restrict__ park, const int* __restrict__ flag)
{
  if (*flag == 0) return;
  const int t = threadIdx.x;
  static const __device__ int segbase8[8] = {
    PX, PW(0), PW(1), PW(2), PW(3), PW(4), PW(5), PW(6) };
  #pragma unroll
  for (int i = 0; i < 8; i++) {
    int gr = blockIdx.x * 8 + i;           // 0..9215
    int seg   = (gr < 2048) ? 0  : 1 + ((gr - 2048) >> 10);
    int inner = (gr < 2048) ? gr : ((gr - 2048) & 1023);
    const float* s = (const float*)src.p[seg] + inner * 1024 + t * 4;
    f32x4 v = *(const f32x4*)s;
    short4v o;
    o.x = (short)f2bf(v.x); o.y = (short)f2bf(v.y);
    o.z = (short)f2bf(v.z); o.w = (short)f2bf(v.w);
    *(short4v*)(park + segbase8[seg] + inner * 1024 + t * 4) = o;
  }
}

// ---------------------------------------------------------------------------
// K1: Y[2048,6144] bf16 = X[2048,1024] @ [Wq Wk Wv cWq cWk cWv]^T
// R16-proven: 128x128 tile, 2-phase double-buffer, two barriers, vmcnt(4),
// XCD-bijective swizzle (768 = 8 x 96). X/W base selected by flag.
// launch_bounds(256,2): counted-vmcnt requires no spills (R20 lesson).
// ---------------------------------------------------------------------------
__global__ __launch_bounds__(256, 2) void k_proj_gemm(
    const unsigned short* __restrict__ Xpark, const unsigned short* __restrict__ Xdir,
    W6 w6park, W6 w6dir, const int* __restrict__ flag,
    unsigned short* __restrict__ Y)
{
  __shared__ unsigned short As[2][128 * 32];
  __shared__ unsigned short Bs[2][128 * 32];
  const int t = threadIdx.x;
  const int lane = t & 63, wid = t >> 6;
  const int f32m = *flag;
  const unsigned short* X = f32m ? Xpark : Xdir;
  int bid = blockIdx.y * 16 + blockIdx.x;
  bid = (bid & 7) * 96 + (bid >> 3);            // XCD chunking (768 % 8 == 0)
  const int m0 = (bid & 15) * 128;
  const int bn = bid >> 4;                      // 0..47
  const unsigned short* W = f32m ? w6park.p[bn >> 3] : w6dir.p[bn >> 3];
  const int nw0 = (bn & 7) * 128;
  const int waveM = (wid & 1) * 64, waveN = (wid >> 1) * 64;
  const int g = lane >> 4, c16 = lane & 15;
  const int srow = t >> 2, scol = (t & 3) * 8;

  f32x4 acc[4][4];
  #pragma unroll
  for (int i = 0; i < 4; i++)
    #pragma unroll
    for (int j = 0; j < 4; j++) acc[i][j] = f32x4{0.f, 0.f, 0.f, 0.f};

#define PSTAGE(bi, k0_) do { \
    async16(X + (size_t)(m0 + srow) * 1024 + (k0_) + scol,       (char*)As[bi] + t * 16); \
    async16(X + (size_t)(m0 + 64 + srow) * 1024 + (k0_) + scol,  (char*)As[bi] + 4096 + t * 16); \
    async16(W + (size_t)(nw0 + srow) * 1024 + (k0_) + scol,      (char*)Bs[bi] + t * 16); \
    async16(W + (size_t)(nw0 + 64 + srow) * 1024 + (k0_) + scol, (char*)Bs[bi] + 4096 + t * 16); \
  } while (0)

  PSTAGE(0, 0);
  for (int k0 = 0; k0 < 1024; k0 += 32) {
    const int cur = (k0 >> 5) & 1;
    if (k0 < 992) {
      PSTAGE(cur ^ 1, k0 + 32);                 // prefetch next K-tile
      __builtin_amdgcn_sched_barrier(0);
      asm volatile("s_waitcnt vmcnt(4)" ::: "memory");   // current tile landed
    } else {
      __builtin_amdgcn_sched_barrier(0);
      asm volatile("s_waitcnt vmcnt(0)" ::: "memory");
    }
    __builtin_amdgcn_s_barrier();
    __builtin_amdgcn_sched_barrier(0);
    short8 af[4], bfr[4];
    #pragma unroll
    for (int mt = 0; mt < 4; mt++)
      af[mt] = *(const short8*)(As[cur] + (waveM + mt * 16 + c16) * 32 + g * 8);
    #pragma unroll
    for (int nt = 0; nt < 4; nt++)
      bfr[nt] = *(const short8*)(Bs[cur] + (waveN + nt * 16 + c16) * 32 + g * 8);
    #pragma unroll
    for (int mt = 0; mt < 4; mt++)
      #pragma unroll
      for (int nt = 0; nt < 4; nt++)
        acc[mt][nt] = mfma16(af[mt], bfr[nt], acc[mt][nt]);
    __builtin_amdgcn_sched_barrier(0);
    __builtin_amdgcn_s_barrier();               // reads done before next stage
  }
#undef PSTAGE
  const int n0 = bn * 128;
  #pragma unroll
  for (int mt = 0; mt < 4; mt++)
    #pragma unroll
    for (int nt = 0; nt < 4; nt++)
      #pragma unroll
      for (int r = 0; r < 4; r++) {
        int row = m0 + waveM + mt * 16 + g * 4 + r;
        int col = n0 + waveN + nt * 16 + c16;
        Y[(size_t)row * 6144 + col] = f2bf(acc[mt][nt][r]);
      }
}

// ---------------------------------------------------------------------------
// K2: per (b,l) row: LN+rope(q,k), rope(v), copy(cq,ck,cv); transpose layouts.
// R16-proven body + R21 XCD-bijective block remap (2048 = 8 x 256).
// ---------------------------------------------------------------------------
__global__ __launch_bounds__(256) void k_post(
    const unsigned short* __restrict__ Y,
    const unsigned short* __restrict__ qg, const unsigned short* __restrict__ qbv,
    const unsigned short* __restrict__ kg, const unsigned short* __restrict__ kbv,
    const int* __restrict__ idx,
    unsigned short* __restrict__ qo, unsigned short* __restrict__ ko,
    unsigned short* __restrict__ cqo, unsigned short* __restrict__ cko,
    unsigned short* __restrict__ vto, unsigned short* __restrict__ cvto)
{
  const int bidr = blockIdx.x;
  const int r = (bidr & 7) * 256 + (bidr >> 3);   // XCD-contiguous row stripes
  const int b = r >> 10, l = r & 1023;
  const int t = threadIdx.x;
  __shared__ float red[4];
  __shared__ float rowbuf[1024];
  __shared__ float tc[32], ts[32];
  const unsigned short* Yr = Y + (size_t)r * 6144;
  const float pos = (float)idx[r];

  if (t < 32) {
    float a = pos * freq_of(t);
    tc[t] = cosf(a);
    ts[t] = sinf(a);
  }
  __syncthreads();

  for (int sec = 0; sec < 2; sec++) {
    const unsigned short* src = Yr + sec * 1024;
    const unsigned short* gg = sec ? kg : qg;
    const unsigned short* bb = sec ? kbv : qbv;
    unsigned short* dst = sec ? ko : qo;
    float v0 = bf2f(src[t]), v1 = bf2f(src[t + 256]);
    float v2 = bf2f(src[t + 512]), v3 = bf2f(src[t + 768]);
    float s = v0 + v1 + v2 + v3;
    float s2 = v0 * v0 + v1 * v1 + v2 * v2 + v3 * v3;
    #pragma unroll
    for (int o = 32; o > 0; o >>= 1) {
      s += __shfl_down(s, o, 64);
      s2 += __shfl_down(s2, o, 64);
    }
    __syncthreads();
    if ((t & 63) == 0) red[t >> 6] = s;
    __syncthreads();
    float tot = red[0] + red[1] + red[2] + red[3];
    __syncthreads();
    if ((t & 63) == 0) red[t >> 6] = s2;
    __syncthreads();
    float tot2 = red[0] + red[1] + red[2] + red[3];
    float mu = tot * (1.f / 1024.f);
    float var = tot2 * (1.f / 1024.f) - mu * mu;
    float rstd = rsqrtf(var + 1e-5f);
    rowbuf[t]       = (v0 - mu) * rstd * bf2f(gg[t])       + bf2f(bb[t]);
    rowbuf[t + 256] = (v1 - mu) * rstd * bf2f(gg[t + 256]) + bf2f(bb[t + 256]);
    rowbuf[t + 512] = (v2 - mu) * rstd * bf2f(gg[t + 512]) + bf2f(bb[t + 512]);
    rowbuf[t + 768] = (v3 - mu) * rstd * bf2f(gg[t + 768]) + bf2f(bb[t + 768]);
    __syncthreads();
    #pragma unroll
    for (int j = 0; j < 4; j++) {
      int d = t + 256 * j;
      int h = d >> 6, dd = d & 63;
      float c = tc[dd & 31], sn = ts[dd & 31];
      float x1 = rowbuf[d];
      float x2 = rowbuf[(d & ~63) | ((dd + 32) & 63)];
      float res = (dd < 32) ? (x1 * c - x2 * sn) : (x1 * c + x2 * sn);
      dst[((size_t)(b * 16 + h) * 1024 + l) * 64 + dd] = f2bf(res);
    }
  }
  {
    const unsigned short* src = Yr + 2048;
    __syncthreads();
    rowbuf[t] = bf2f(src[t]); rowbuf[t + 256] = bf2f(src[t + 256]);
    rowbuf[t + 512] = bf2f(src[t + 512]); rowbuf[t + 768] = bf2f(src[t + 768]);
    __syncthreads();
    #pragma unroll
    for (int j = 0; j < 4; j++) {
      int d = t + 256 * j;
      int h = d >> 6, dd = d & 63;
      float c = tc[dd & 31], sn = ts[dd & 31];
      float x1 = rowbuf[d];
      float x2 = rowbuf[(d & ~63) | ((dd + 32) & 63)];
      float res = (dd < 32) ? (x1 * c - x2 * sn) : (x1 * c + x2 * sn);
      vto[((size_t)(b * 16 + h) * 64 + dd) * 1024 + l] = f2bf(res);
    }
  }
  #pragma unroll
  for (int j = 0; j < 4; j++) {
    int d = t + 256 * j;
    int h = d >> 6, dd = d & 63;
    size_t km = ((size_t)(b * 16 + h) * 1024 + l) * 64 + dd;
    cqo[km] = Yr[3072 + d];
    cko[km] = Yr[4096 + d];
    cvto[((size_t)(b * 16 + h) * 64 + dd) * 1024 + l] = Yr[5120 + d];
  }
}

// ---------------------------------------------------------------------------
// K3: flash attention (no online max; LN'd q/k => bounded scores).
// R23: R15 body with Ps/Pc per-strip dim removed (strips time-share one
// wave-private buffer; in-wave LDS ordering makes it sync-free). LDS
// 60.4KB -> 49.8KB => 3 blocks/CU resident. Grid (8,32,2) = 512 blocks.
// ---------------------------------------------------------------------------
__global__ __launch_bounds__(256, 2) void k_attn(
    const unsigned short* __restrict__ qm, const unsigned short* __restrict__ km,
    const unsigned short* __restrict__ cqm, const unsigned short* __restrict__ ckm,
    const unsigned short* __restrict__ vt, const unsigned short* __restrict__ cvt,
    const int* __restrict__ chain, const int* __restrict__ mol,
    const unsigned char* __restrict__ zpk, const unsigned short* __restrict__ bias,
    float* __restrict__ Opart, float* __restrict__ lpart)
{
  const int q0 = blockIdx.x * 128;
  const int bh = blockIdx.y;
  const int seg = blockIdx.z;                 // 0..1
  const int b = bh >> 4, h = bh & 15;
  __shared__ float biasf[64];
  __shared__ unsigned char codek[512];
  __shared__ __align__(16) unsigned char zs[128 * 64];                // 8 KB
  __shared__ __align__(16) unsigned short Ks[64 * 64], cKs[64 * 64];  // 8 KB each
  __shared__ __align__(16) unsigned short Vs[64 * 64], cVs[64 * 64];  // 8 KB each
  __shared__ unsigned short Ps[4][16][36], Pc[4][16][36];             // 4.5 KB each
  const int t = threadIdx.x, lane = t & 63, w = t >> 6;   // w in 0..3
  const int g = lane >> 4, c16 = lane & 15;
  const int kbeg = seg * 512;

  if (t < 128) {
    int4 ch = *(const int4*)(chain + b * 1024 + kbeg + t * 4);
    int4 mo = *(const int4*)(mol   + b * 1024 + kbeg + t * 4);
    codek[t * 4 + 0] = mo.x ? 255 : (unsigned char)ch.x;
    codek[t * 4 + 1] = mo.y ? 255 : (unsigned char)ch.y;
    codek[t * 4 + 2] = mo.z ? 255 : (unsigned char)ch.z;
    codek[t * 4 + 3] = mo.w ? 255 : (unsigned char)ch.w;
  } else if (t < 192) {
    biasf[t - 128] = bf2f(bias[(t - 128) * 16 + h]);
  }

  const size_t basep = (size_t)bh << 16;      // bh * 64 * 1024
  int cqa[2][4];
  #pragma unroll
  for (int s = 0; s < 2; s++) {
    int4 cqv = *(const int4*)(chain + b * 1024 + q0 + s * 64 + w * 16 + g * 4);
    cqa[s][0] = cqv.x; cqa[s][1] = cqv.y; cqa[s][2] = cqv.z; cqa[s][3] = cqv.w;
  }

  // q / cq fragments: invariant across chunks — load once (32 VGPR).
  short8 aq0[2], aq1[2], acq0[2], acq1[2];
  #pragma unroll
  for (int s = 0; s < 2; s++) {
    const unsigned short* qrow  = qm  + basep + (size_t)(q0 + s * 64 + w * 16 + c16) * 64;
    const unsigned short* cqrow = cqm + basep + (size_t)(q0 + s * 64 + w * 16 + c16) * 64;
    aq0[s]  = *(const short8*)(qrow + g * 8);
    aq1[s]  = *(const short8*)(qrow + 32 + g * 8);
    acq0[s] = *(const short8*)(cqrow + g * 8);
    acq1[s] = *(const short8*)(cqrow + 32 + g * 8);
  }

  float l_[2][4];
  f32x4 Os[2][4], Oc[2][4];
  #pragma unroll
  for (int s = 0; s < 2; s++)
    #pragma unroll
    for (int nt = 0; nt < 4; nt++) {
      l_[s][nt] = 0.f;
      Os[s][nt] = f32x4{0.f, 0.f, 0.f, 0.f};
      Oc[s][nt] = f32x4{0.f, 0.f, 0.f, 0.f};
    }
  // Staging lane roles (R11/R12-proven patterns)
  const int Rk = t >> 3, jk = t & 7;          // K/V tiles: 32 rows x 8 groups/issue
  const int Rz = t >> 2, jz = t & 3;          // zs: 64 rows x 4 groups/issue
  const int swz16 = (jz ^ ((Rz >> 2) & 3)) * 16;      // byte offset, zs swizzle
  const f32x4 zero = f32x4{0.f, 0.f, 0.f, 0.f};
  __syncthreads();   // codek/biasf ready

  for (int kc = 0; kc < 8; kc++) {
    const int kt = kbeg + kc * 64;
    // stage zs (128 q-rows x 64 keys, this chunk), group-swizzled source
    #pragma unroll
    for (int i = 0; i < 2; i++)
      async16(zpk + (size_t)b * 1048576 + (size_t)(q0 + i * 64 + Rz) * 1024
                  + kt + swz16,
              (char*)zs + i * 4096 + t * 16);
    // stage K/cK (64 keys x 64 d) and V/cV (64 d x 64 keys), swizzled
    #pragma unroll
    for (int i = 0; i < 2; i++) {
      int row = i * 32 + Rk;
      int srcb = jk ^ (row & 7);
      async16(km  + basep + (size_t)(kt + row) * 64 + srcb * 8, (char*)Ks  + i * 4096 + t * 16);
      async16(ckm + basep + (size_t)(kt + row) * 64 + srcb * 8, (char*)cKs + i * 4096 + t * 16);
      async16(vt  + basep + (size_t)row * 1024 + kt + srcb * 8, (char*)Vs  + i * 4096 + t * 16);
      async16(cvt + basep + (size_t)row * 1024 + kt + srcb * 8, (char*)cVs + i * 4096 + t * 16);
    }
    __syncthreads();
    // --- per 32-key half: QK (frag-shared), exp per strip, PV (frag-shared)
    #pragma unroll
    for (int half = 0; half < 2; half++) {
      // scores for this half's 2 key-col-frags, both strips
      f32x4 sS[2][2], sC[2][2];
      #pragma unroll
      for (int nn = 0; nn < 2; nn++) {
        int R = (half * 2 + nn) * 16 + c16;
        int sw = R & 7;
        short8 kbl = *(const short8*)((char*)Ks  + R * 128 + ((g ^ sw) * 16));
        short8 kbh = *(const short8*)((char*)Ks  + R * 128 + (((4 + g) ^ sw) * 16));
        short8 cbl = *(const short8*)((char*)cKs + R * 128 + ((g ^ sw) * 16));
        short8 cbh = *(const short8*)((char*)cKs + R * 128 + (((4 + g) ^ sw) * 16));
        #pragma unroll
        for (int s = 0; s < 2; s++) {
          sS[s][nn] = mfma16(aq1[s], kbh, mfma16(aq0[s], kbl, zero));
          sC[s][nn] = mfma16(acq1[s], cbh, mfma16(acq0[s], cbl, zero));
        }
      }
      int cd0 = codek[kc * 64 + half * 32 + c16];
      int cd1 = codek[kc * 64 + half * 32 + 16 + c16];
      short8 aps[2], apc[2];
      #pragma unroll
      for (int s = 0; s < 2; s++) {
        // write strip s's P into the wave-private buffer, then read its
        // fragments into registers BEFORE the next strip overwrites it
        // (in-wave LDS ordering; compiler sees the same-array dependency).
        #pragma unroll
        for (int r = 0; r < 4; r++) {
          const unsigned char* zr = zs + (s * 64 + w * 16 + g * 4 + r) * 64;
          // source group (half*2+k) lives at LDS group (half*2+k)^g for our rows
          float bi0 = biasf[zr[((half * 2) ^ g) * 16 + c16]];
          float bi1 = biasf[zr[((half * 2 + 1) ^ g) * 16 + c16]];
          bool sp0 = (cd0 == cqa[s][r]);
          bool sp1 = (cd1 == cqa[s][r]);
          float p0 = __expf(__fmaf_rn(sp0 ? sS[s][0][r] : sC[s][0][r], 0.125f, bi0));
          float p1 = __expf(__fmaf_rn(sp1 ? sS[s][1][r] : sC[s][1][r], 0.125f, bi1));
          l_[s][r] += p0 + p1;
          int lr = g * 4 + r;
          Ps[w][lr][c16]      = f2bf_rz(sp0 ? p0 : 0.f);
          Pc[w][lr][c16]      = f2bf_rz(sp0 ? 0.f : p0);
          Ps[w][lr][16 + c16] = f2bf_rz(sp1 ? p1 : 0.f);
          Pc[w][lr][16 + c16] = f2bf_rz(sp1 ? 0.f : p1);
        }
        aps[s] = *(const short8*)&Ps[w][c16][g * 8];
        apc[s] = *(const short8*)&Pc[w][c16][g * 8];
      }
      // PV: V-frags shared across strips
      #pragma unroll
      for (int nt = 0; nt < 4; nt++) {
        int R = nt * 16 + c16;
        int sw = R & 7;
        int J = half * 4 + g;
        short8 bv  = *(const short8*)((char*)Vs  + R * 128 + ((J ^ sw) * 16));
        short8 bcv = *(const short8*)((char*)cVs + R * 128 + ((J ^ sw) * 16));
        #pragma unroll
        for (int s = 0; s < 2; s++) {
          Os[s][nt] = mfma16(aps[s], bv,  Os[s][nt]);
          Oc[s][nt] = mfma16(apc[s], bcv, Oc[s][nt]);
        }
      }
    }
    __syncthreads();   // protect tiles/zs before next chunk's staging
  }

  // epilogue: reduce l across the quad-group lanes; store partials
  #pragma unroll
  for (int s = 0; s < 2; s++)
    #pragma unroll
    for (int r = 0; r < 4; r++) {
      float lv = l_[s][r];
      lv += __shfl_xor(lv, 1);
      lv += __shfl_xor(lv, 2);
      lv += __shfl_xor(lv, 4);
      lv += __shfl_xor(lv, 8);
      int row = q0 + s * 64 + w * 16 + g * 4 + r;
      float* op = Opart + (((size_t)seg * 32 + bh) * 1024 + row) * 128;
      #pragma unroll
      for (int nt = 0; nt < 4; nt++) {
        op[nt * 16 + c16]      = Os[s][nt][r];
        op[64 + nt * 16 + c16] = Oc[s][nt][r];
      }
      if (c16 == 0) lpart[((size_t)seg * 32 + bh) * 1024 + row] = lv;
    }
}

// ---------------------------------------------------------------------------
// K3b: combine 2 K-segment partials (linear), normalize, inverse rope, write
// comb (B,L,D) bf16.
// ---------------------------------------------------------------------------
__global__ __launch_bounds__(256) void k_combine(
    const float* __restrict__ Opart, const float* __restrict__ lpart,
    const int* __restrict__ idx, unsigned short* __restrict__ comb)
{
  const int t = threadIdx.x;
  const int rg = blockIdx.x * 8 + (t >> 5);   // global row id in [0, 32768)
  const int d = t & 31;
  const int bh = rg >> 10, row = rg & 1023;
  const int b = bh >> 4, h = bh & 15;
  float oslo = 0.f, oshi = 0.f, oclo = 0.f, ochi = 0.f, l = 0.f;
  #pragma unroll
  for (int seg = 0; seg < 2; seg++) {
    const float* op = Opart + (((size_t)seg * 32 + bh) * 1024 + row) * 128;
    oslo += op[d]; oshi += op[32 + d];
    oclo += op[64 + d]; ochi += op[96 + d];
    l += lpart[((size_t)seg * 32 + bh) * 1024 + row];
  }
  float inv = 1.f / l;
  float pos = (float)idx[b * 1024 + row];
  float fr = freq_of(d);
  float aa = -pos * fr;
  float cc = cosf(aa), sn = sinf(aa);
  size_t orow = ((size_t)(b * 1024 + row)) * 1024 + h * 64;
  comb[orow + d]      = f2bf((oslo * cc - oshi * sn + oclo) * inv);
  comb[orow + d + 32] = f2bf((oshi * cc + oslo * sn + ochi) * inv);
}

// ---------------------------------------------------------------------------
// K4: out = comb @ Wo^T ; store bf16 or fp32 depending on detected dtype.
// R16-proven: 64x128 tiles, 256 blocks, two-barrier 2-phase double-buffer,
// counted vmcnt(3), XCD-bijective swizzle. Wo base selected by flag.
// ---------------------------------------------------------------------------
__global__ __launch_bounds__(256, 2) void k_out_gemm(
    const unsigned short* __restrict__ A,
    const unsigned short* __restrict__ Wopark, const unsigned short* __restrict__ Wodir,
    const int* __restrict__ flag, void* __restrict__ outv)
{
  __shared__ unsigned short As[2][64 * 32];
  __shared__ unsigned short Bs[2][128 * 32];
  const int t = threadIdx.x;
  const int lane = t & 63, wid = t >> 6;
  const int f32out = *flag;
  const unsigned short* Wo = f32out ? Wopark : Wodir;
  int bid = blockIdx.y * 32 + blockIdx.x;
  bid = (bid & 7) * 32 + (bid >> 3);            // XCD chunking (256 % 8 == 0)
  const int m0 = (bid & 31) * 64;
  const int n0 = (bid >> 5) * 128;
  const int waveM = (wid & 1) * 32, waveN = (wid >> 1) * 64;
  const int g = lane >> 4, c16 = lane & 15;
  const int srow = t >> 2, scol = (t & 3) * 8;  // A: 64 rows x 4 col-groups
  f32x4 acc[2][4];
  #pragma unroll
  for (int i = 0; i < 2; i++)
    #pragma unroll
    for (int j = 0; j < 4; j++) acc[i][j] = f32x4{0.f, 0.f, 0.f, 0.f};

#define OSTAGE(bi, k0_) do { \
    async16(A  + (size_t)(m0 + srow) * 1024 + (k0_) + scol,       (char*)As[bi] + t * 16); \
    async16(Wo + (size_t)(n0 + srow) * 1024 + (k0_) + scol,       (char*)Bs[bi] + t * 16); \
    async16(Wo + (size_t)(n0 + 64 + srow) * 1024 + (k0_) + scol,  (char*)Bs[bi] + 4096 + t * 16); \
  } while (0)

  OSTAGE(0, 0);
  for (int k0 = 0; k0 < 1024; k0 += 32) {
    const int cur = (k0 >> 5) & 1;
    if (k0 < 992) {
      OSTAGE(cur ^ 1, k0 + 32);
      __builtin_amdgcn_sched_barrier(0);
      asm volatile("s_waitcnt vmcnt(3)" ::: "memory");
    } else {
      __builtin_amdgcn_sched_barrier(0);
      asm volatile("s_waitcnt vmcnt(0)" ::: "memory");
    }
    __builtin_amdgcn_s_barrier();
    __builtin_amdgcn_sched_barrier(0);
    short8 af[2], bfr[4];
    #pragma unroll
    for (int mt = 0; mt < 2; mt++)
      af[mt] = *(const short8*)(As[cur] + (waveM + mt * 16 + c16) * 32 + g * 8);
    #pragma unroll
    for (int nt = 0; nt < 4; nt++)
      bfr[nt] = *(const short8*)(Bs[cur] + (waveN + nt * 16 + c16) * 32 + g * 8);
    #pragma unroll
    for (int mt = 0; mt < 2; mt++)
      #pragma unroll
      for (int nt = 0; nt < 4; nt++)
        acc[mt][nt] = mfma16(af[mt], bfr[nt], acc[mt][nt]);
    __builtin_amdgcn_sched_barrier(0);
    __builtin_amdgcn_s_barrier();
  }
#undef OSTAGE
  #pragma unroll
  for (int mt = 0; mt < 2; mt++)
    #pragma unroll
    for (int nt = 0; nt < 4; nt++)
      #pragma unroll
      for (int r = 0; r < 4; r++) {
        int row = m0 + waveM + mt * 16 + g * 4 + r;
        int col = n0 + waveN + nt * 16 + c16;
        if (f32out) ((float*)outv)[(size_t)row * 1024 + col] = acc[mt][nt][r];
        else ((unsigned short*)outv)[(size_t)row * 1024 + col] = f2bf(acc[mt][nt][r]);
      }
}

// ---------------------------------------------------------------------------
extern "C" void kernel_launch(void* const* d_in, const int* in_sizes, int n_in,
                              void* d_out, int out_size, void* d_ws, size_t ws_size,
                              hipStream_t stream)
{
  (void)in_sizes; (void)n_in; (void)out_size; (void)ws_size;
  const int* z     = (const int*)d_in[1];
  const int* idx   = (const int*)d_in[3];
  const int* chain = (const int*)d_in[4];
  const int* mol   = (const int*)d_in[5];

  char* ws = (char*)d_ws;
  unsigned short* Y     = (unsigned short*)ws;              // 25 MB bf16
  size_t off = 50331648;
  unsigned short* qbuf  = (unsigned short*)(ws + off); off += 4194304;
  unsigned short* kbuf  = (unsigned short*)(ws + off); off += 4194304;
  unsigned short* cqbuf = (unsigned short*)(ws + off); off += 4194304;
  unsigned short* ckbuf = (unsigned short*)(ws + off); off += 4194304;
  unsigned short* vtbuf = (unsigned short*)(ws + off); off += 4194304;
  unsigned short* cvtbuf= (unsigned short*)(ws + off); off += 4194304;
  unsigned short* comb  = (unsigned short*)(ws + off); off += 4194304;
  unsigned short* park  = (unsigned short*)(ws + off); off += (size_t)PARK_TOTAL * 2;
  unsigned char*  zpk   = (unsigned char*)(ws + off); off += 2097152;
  float*          Opart = (float*)(ws + off); off += (size_t)2 * 32 * 1024 * 128 * 4;
  float*          lpart = (float*)(ws + off); off += (size_t)2 * 32 * 1024 * 4;
  int*            flag  = (int*)(ws + off);

  Src13 src;
  src.p[0]  = d_in[0];   // x
  src.p[1]  = d_in[6];   // Wq
  src.p[2]  = d_in[7];   // Wk
  src.p[3]  = d_in[8];   // Wv
  src.p[4]  = d_in[9];   // Wo
  src.p[5]  = d_in[10];  // cWq
  src.p[6]  = d_in[11];  // cWk
  src.p[7]  = d_in[12];  // cWv
  src.p[8]  = d_in[13];  // qg
  src.p[9]  = d_in[14];  // qb
  src.p[10] = d_in[15];  // kg
  src.p[11] = d_in[16];  // kb
  src.p[12] = d_in[17];  // attn_bias

  W6 w6park, w6dir;
  w6park.p[0] = park + PW(0);  // Wq
  w6park.p[1] = park + PW(1);  // Wk
  w6park.p[2] = park + PW(2);  // Wv
  w6park.p[3] = park + PW(4);  // cWq
  w6park.p[4] = park + PW(5);  // cWk
  w6park.p[5] = park + PW(6);  // cWv
  w6dir.p[0] = (const unsigned short*)d_in[6];   // Wq
  w6dir.p[1] = (const unsigned short*)d_in[7];   // Wk
  w6dir.p[2] = (const unsigned short*)d_in[8];   // Wv
  w6dir.p[3] = (const unsigned short*)d_in[10];  // cWq
  w6dir.p[4] = (const unsigned short*)d_in[11];  // cWk
  w6dir.p[5] = (const unsigned short*)d_in[12];  // cWv

  k_convert<<<2049, 256, 0, stream>>>(src, park, z, zpk, flag);
  k_park<<<1152, 256, 0, stream>>>(src, park, flag);
  k_proj_gemm<<<dim3(16, 48), 256, 0, stream>>>(
      park + PX, (const unsigned short*)d_in[0], w6park, w6dir, flag, Y);
  k_post<<<2048, 256, 0, stream>>>(Y, park + PQG, park + PQB, park + PKG, park + PKB,
                                   idx, qbuf, kbuf, cqbuf, ckbuf, vtbuf, cvtbuf);
  k_attn<<<dim3(8, 32, 2), 256, 0, stream>>>(qbuf, kbuf, cqbuf, ckbuf, vtbuf, cvtbuf,
                                             chain, mol, zpk, park + PBI,
                                             Opart, lpart);
  k_combine<<<4096, 256, 0, stream>>>(Opart, lpart, idx, comb);
  k_out_gemm<<<dim3(32, 8), 256, 0, stream>>>(
      comb, park + PW(3), (const unsigned short*)d_in[9], flag, d_out);
}